// Round 6
// baseline (234.028 us; speedup 1.0000x reference)
//
#include <hip/hip_runtime.h>

#define NI 2048
#define NB 64
#define NC 32
#define DC 16
#define DI 8

static constexpr float SQ_EPS = 1e-7f;

// SSA vector type: first-class LLVM vector -> never an alloca, never scratch.
typedef float f8 __attribute__((ext_vector_type(8)));

union F8u { f8 v; float4 q[2]; };

// Routing pass v7 — v2's 512-thread structure + the PROVEN register attrs.
// Occupancy history: v1/v5/v6 (256 thr, 512 blocks) were GRID-limited:
// 512 wg x 4 waves = 2048 waves / 256 CU = 8 waves/CU (Occupancy 17-19%
// regardless of LDS size). v2/v3 had the right structure (512 thr -> 4096
// waves = 16/CU) but waves_per_eu(4[,4]) imposed a 64-VGPR budget
// (toolchain law, triple-confirmed: arch-VGPR budget = 256/min_waves_per_eu)
// -> spill -> 118 us/pass. v6 lesson: wave-uniform global x loads stall the
// il-step head at low occupancy; keep x in LDS.
// v7 = v2 body + waves_per_eu(2,2): budget 128 >= 112-reg live set, no
// spill; runtime occupancy from grid+resources: 4096 waves, 112 VGPR ->
// 4 waves/EU, LDS 75.8 KB -> 2 blocks/CU => 16 waves/CU.
// Grid (128 i-blocks, 4 b-quarters) x 512 threads (8 waves).
// Block = 16 b x 16 i. Wave w: bq = w&3 (owns b-quad by*16 + bq*4 + {0..3}),
// ih = w>>2 (owns i-half). Per round (4 rounds) stage 2 i from each half
// (4 i-slots); each wave consumes its half's 2 slots. Per-wave arithmetic
// (4-b amortization of W fragments, ds_read count, pair-softmax) identical
// to v1. End: cross-ih reduce through LDS; partial layout unchanged.
// Lane = (c = lane&31, dg = lane>>5).
// MODE 0: uniform coupling 1/32. MODE 1: logits = dot(u, veff),
// veff transposed [b][dg][c][8].
template <int MODE>
__global__
__attribute__((amdgpu_flat_work_group_size(512, 512), amdgpu_waves_per_eu(2, 2)))
void route_pass(
    const float* __restrict__ x, const float* __restrict__ W,
    const float* __restrict__ veff, float* __restrict__ partial)
{
    // W slots: float4 [slot 4 = ih*2+il][k10 16][kdg 2][c 32 + 1 pad]
    __shared__ float4 wbuf[4224];   // 67.6 KB
    __shared__ float4 xbuf[512];    // [brel 16][iloc 16][2] = 8 KB, staged once

    const int tid   = threadIdx.x;
    const int wave  = tid >> 6;
    const int lane  = tid & 63;
    const int c     = lane & 31;
    const int dg    = lane >> 5;
    const int bq    = wave & 3;
    const int ih    = wave >> 2;
    const int brel0 = bq * 4;
    const int b0    = blockIdx.y * 16 + brel0;    // wave's b-quad base
    const int i0    = blockIdx.x * 16;

    f8 s0 = {}, s1 = {}, s2 = {}, s3 = {};

    // veff fragments for the 4 b's (MODE 1), transposed [b][dg][c][8]
    f8 va = {}, vb = {}, vc = {}, vd = {};
    if (MODE == 1) {
        va = *reinterpret_cast<const f8*>(veff + (((size_t)(b0+0)*2 + dg)*32 + c)*8);
        vb = *reinterpret_cast<const f8*>(veff + (((size_t)(b0+1)*2 + dg)*32 + c)*8);
        vc = *reinterpret_cast<const f8*>(veff + (((size_t)(b0+2)*2 + dg)*32 + c)*8);
        vd = *reinterpret_cast<const f8*>(veff + (((size_t)(b0+3)*2 + dg)*32 + c)*8);
    }

    // ---- stage x once for all 16 i (coalesced 512 B per b-row)
    {
        const int brel = tid >> 5;
        const int q    = tid & 31;
        xbuf[tid] = reinterpret_cast<const float4*>(x)[
            ((size_t)(blockIdx.y * 16 + brel) * NI + i0) * 2 + q];
    }

    for (int rnd = 0; rnd < 4; ++rnd) {
        __syncthreads();               // previous round's readers done
        // ---- stage W: 4 i-rows (2 per half) x 32 c = 128 rows x 512 B
        {
            const int k    = tid & 31;        // float4 within a (c,i) row
            const int rowp = tid >> 5;        // 0..15
            const int k10 = k & 15, kdg = k >> 4;
#pragma unroll
            for (int r = 0; r < 8; ++r) {
                const int row = r * 16 + rowp;    // 0..127
                const int cc  = row >> 2;
                const int sub = row & 3;          // = slot = iih*2 + iil
                wbuf[((sub * 16 + k10) * 2 + kdg) * 33 + cc] =
                    reinterpret_cast<const float4*>(W)[
                        ((size_t)cc * NI + i0 + (sub >> 1) * 8 + rnd * 2
                         + (sub & 1)) * 32 + k];
            }
        }
        __syncthreads();

#pragma unroll
        for (int il = 0; il < 2; ++il) {
            const int slot = ih * 2 + il;
            const int iloc = ih * 8 + rnd * 2 + il;
            // x broadcast reads (wave-uniform LDS addresses)
            const float4 xa0 = xbuf[(brel0+0)*32 + iloc*2], xa1 = xbuf[(brel0+0)*32 + iloc*2+1];
            const float4 xb0 = xbuf[(brel0+1)*32 + iloc*2], xb1 = xbuf[(brel0+1)*32 + iloc*2+1];
            const float4 xc0 = xbuf[(brel0+2)*32 + iloc*2], xc1 = xbuf[(brel0+2)*32 + iloc*2+1];
            const float4 xd0 = xbuf[(brel0+3)*32 + iloc*2], xd1 = xbuf[(brel0+3)*32 + iloc*2+1];

            f8 u0 = {}, u1 = {}, u2 = {}, u3 = {};
#pragma unroll
            for (int dd = 0; dd < 8; ++dd) {
                const float4 wl = wbuf[((slot*16 + dd*2    )*2 + dg)*33 + c];
                const float4 wh = wbuf[((slot*16 + dd*2 + 1)*2 + dg)*33 + c];
                u0[dd] = wl.x*xa0.x + wl.y*xa0.y + wl.z*xa0.z + wl.w*xa0.w
                       + wh.x*xa1.x + wh.y*xa1.y + wh.z*xa1.z + wh.w*xa1.w;
                u1[dd] = wl.x*xb0.x + wl.y*xb0.y + wl.z*xb0.z + wl.w*xb0.w
                       + wh.x*xb1.x + wh.y*xb1.y + wh.z*xb1.z + wh.w*xb1.w;
                u2[dd] = wl.x*xc0.x + wl.y*xc0.y + wl.z*xc0.z + wl.w*xc0.w
                       + wh.x*xc1.x + wh.y*xc1.y + wh.z*xc1.z + wh.w*xc1.w;
                u3[dd] = wl.x*xd0.x + wl.y*xd0.y + wl.z*xd0.z + wl.w*xd0.w
                       + wh.x*xd1.x + wh.y*xd1.y + wh.z*xd1.z + wh.w*xd1.w;
            }

            if (MODE == 0) {
                const float cu = 1.0f / 32.0f;
                s0 += u0 * cu; s1 += u1 * cu; s2 += u2 * cu; s3 += u3 * cu;
            } else {
                // Pair-softmax: lower 32-half reduces the even b, upper the
                // odd b, concurrently; one xor-32 merge in, one xor-32
                // coef-swap out. 12 shuffles + 1 exp per pair.
#pragma unroll
                for (int pr = 0; pr < 2; ++pr) {
                    const f8& ue = pr ? u2 : u0;
                    const f8& uo = pr ? u3 : u1;
                    const f8& ve = pr ? vc : va;
                    const f8& vo = pr ? vd : vb;
                    float pe = 0.0f, po = 0.0f;
#pragma unroll
                    for (int k = 0; k < 8; ++k) {
                        pe += ue[k] * ve[k];
                        po += uo[k] * vo[k];
                    }
                    // route partial of the OTHER half's b across, keep mine
                    const float send = (dg == 0) ? po : pe;
                    const float recv = __shfl_xor(send, 32);
                    float a = ((dg == 0) ? pe : po) + recv;  // full logit
                    float m = a;
#pragma unroll
                    for (int off = 16; off >= 1; off >>= 1)
                        m = fmaxf(m, __shfl_xor(m, off));
                    const float e = __expf(a - m);
                    float t = e;
#pragma unroll
                    for (int off = 16; off >= 1; off >>= 1)
                        t += __shfl_xor(t, off);
                    const float mine  = e / t;
                    const float other = __shfl_xor(mine, 32);
                    const float ce = (dg == 0) ? mine : other;
                    const float co = (dg == 0) ? other : mine;
                    if (pr == 0) { s0 += u0 * ce; s1 += u1 * co; }
                    else         { s2 += u2 * ce; s3 += u3 * co; }
                }
            }
        }
    }

    // ---- cross-i-half merge: ih=1 waves dump s into (reused) wbuf,
    //      ih=0 waves add and store. Scratch: [brel 16][lane 64][2 f4] = 32 KB.
    __syncthreads();
    const int mbase = (brel0 * 64 + lane) * 2;
    if (ih == 1) {
        F8u t;
        t.v = s0; wbuf[mbase      ] = t.q[0]; wbuf[mbase +   1] = t.q[1];
        t.v = s1; wbuf[mbase + 128] = t.q[0]; wbuf[mbase + 129] = t.q[1];
        t.v = s2; wbuf[mbase + 256] = t.q[0]; wbuf[mbase + 257] = t.q[1];
        t.v = s3; wbuf[mbase + 384] = t.q[0]; wbuf[mbase + 385] = t.q[1];
    }
    __syncthreads();
    if (ih == 0) {
        F8u t;
        t.q[0] = wbuf[mbase      ]; t.q[1] = wbuf[mbase +   1]; s0 += t.v;
        t.q[0] = wbuf[mbase + 128]; t.q[1] = wbuf[mbase + 129]; s1 += t.v;
        t.q[0] = wbuf[mbase + 256]; t.q[1] = wbuf[mbase + 257]; s2 += t.v;
        t.q[0] = wbuf[mbase + 384]; t.q[1] = wbuf[mbase + 385]; s3 += t.v;

        // partial floats: [pblk 512][brel 16][dg 2][c 32][8]  (same as v1)
        const int pblk = blockIdx.y * gridDim.x + blockIdx.x;   // 0..511
        float* gp = partial +
            (((size_t)pblk * 16 + brel0) * 128 + dg * 64 + c * 2) * 4;
        *reinterpret_cast<f8*>(gp)        = s0;
        *reinterpret_cast<f8*>(gp +  512) = s1;
        *reinterpret_cast<f8*>(gp + 1024) = s2;
        *reinterpret_cast<f8*>(gp + 1536) = s3;
    }
}

// Fused 128-way partial reduction + squash, float4-vectorized.
// 64 blocks x 512 threads: tid -> (ibq = tid>>7 sums 32 of the 128 i-block
// slabs; sub = tid&127 -> (c = (sub>>2)&31, dq = sub&3)). 4-way LDS tree
// then squash on tid<128.
// phase 1: veff  = NI * squash(s)   (transposed layout [b][dg][c][8])
// phase 2: veff += NI * squash(s)
// phase 3: out   = squash(s)        (canonical [b][c][d])
__global__ __launch_bounds__(512) void reduce_squash(
    const float* __restrict__ partial, float* __restrict__ veff,
    float* __restrict__ out, int phase)
{
    __shared__ float4 red[512];
    const int b   = blockIdx.x;
    const int sub = threadIdx.x & 127;
    const int ibq = threadIdx.x >> 7;        // i-block quarter
    const int c   = (sub >> 2) & 31;
    const int dq  = sub & 3;                 // d-quad: d = dq*4 + j

    // slab layout: [by*128 + ib][brel 16][dg 2][c 32][8]
    const float* base = partial
        + ((size_t)(b >> 4) * 2048 + (b & 15)) * 512
        + (dq >> 1) * 256 + c * 8 + (dq & 1) * 4
        + (size_t)ibq * 32 * 8192;
    float4 acc = make_float4(0.f, 0.f, 0.f, 0.f);
#pragma unroll 8
    for (int ib = 0; ib < 32; ++ib) {
        const float4 p = *reinterpret_cast<const float4*>(base + (size_t)ib * 8192);
        acc.x += p.x; acc.y += p.y; acc.z += p.z; acc.w += p.w;
    }
    red[threadIdx.x] = acc;
    __syncthreads();
    if (threadIdx.x < 128) {
        const float4 a1 = red[sub + 128];
        const float4 a2 = red[sub + 256];
        const float4 a3 = red[sub + 384];
        acc.x += a1.x + a2.x + a3.x;
        acc.y += a1.y + a2.y + a3.y;
        acc.z += a1.z + a2.z + a3.z;
        acc.w += a1.w + a2.w + a3.w;

        // |s|^2 across the 4 d-quads (dq = low 2 bits of lane id)
        float sq = acc.x*acc.x + acc.y*acc.y + acc.z*acc.z + acc.w*acc.w;
        sq += __shfl_xor(sq, 1);
        sq += __shfl_xor(sq, 2);
        const float scale = sq / ((1.0f + sq) * sqrtf(sq + SQ_EPS));

        if (phase == 3) {
            float4* op = reinterpret_cast<float4*>(out + ((size_t)b * NC + c) * DC + dq * 4);
            *op = make_float4(scale*acc.x, scale*acc.y, scale*acc.z, scale*acc.w);
        } else {
            const float ns = scale * (float)NI;
            float4* vp = reinterpret_cast<float4*>(
                veff + (((size_t)b * 2 + (dq >> 1)) * 32 + c) * 8 + (dq & 1) * 4);
            if (phase == 1) {
                *vp = make_float4(ns*acc.x, ns*acc.y, ns*acc.z, ns*acc.w);
            } else {
                float4 old = *vp;
                *vp = make_float4(old.x + ns*acc.x, old.y + ns*acc.y,
                                  old.z + ns*acc.z, old.w + ns*acc.w);
            }
        }
    }
}

extern "C" void kernel_launch(void* const* d_in, const int* in_sizes, int n_in,
                              void* d_out, int out_size, void* d_ws, size_t ws_size,
                              hipStream_t stream) {
    (void)in_sizes; (void)n_in; (void)out_size; (void)ws_size;
    const float* x = (const float*)d_in[0];
    const float* W = (const float*)d_in[1];

    float* partial = (float*)d_ws;      // 512 slabs x 32 KB = 16 MiB
    float* veff    = (float*)d_out;     // scratch; phase-3 squash overwrites

    const dim3 grid(128, 4);

    // ---- iteration 1: uniform coupling
    route_pass<0><<<grid, 512, 0, stream>>>(x, W, nullptr, partial);
    reduce_squash<<<64, 512, 0, stream>>>(partial, veff, nullptr, 1);

    // ---- iteration 2: logits = NI * <u, v1>
    route_pass<1><<<grid, 512, 0, stream>>>(x, W, veff, partial);
    reduce_squash<<<64, 512, 0, stream>>>(partial, veff, nullptr, 2);

    // ---- iteration 3: logits = NI * (<u, v1> + <u, v2>)
    route_pass<1><<<grid, 512, 0, stream>>>(x, W, veff, partial);
    reduce_squash<<<64, 512, 0, stream>>>(partial, nullptr, (float*)d_out, 3);
}

// Round 7
// 232.724 us; speedup vs baseline: 1.0056x; 1.0056x over previous
//
#include <hip/hip_runtime.h>

#define NI 2048
#define NB 64
#define NC 32
#define DC 16
#define DI 8

static constexpr float SQ_EPS = 1e-7f;

// SSA vector type: first-class LLVM vector -> never an alloca, never scratch.
typedef float f8 __attribute__((ext_vector_type(8)));

union F8u { f8 v; float4 q[2]; };

// Routing pass v8 — v7 body, waves_per_eu max UNCLAMPED.
// Toolchain law (six data points, v1-v7):
//   * waves_per_eu MIN sets codegen arch-VGPR budget = 256/min
//     (min=4 -> 64 regs -> spill, 118-131 us/pass; min=2 -> 128 -> fits).
//   * waves_per_eu MAX clamps RUNTIME waves/EU (v7: (2,2) ran ~2/EU,
//     Occupancy ~20%, despite 4096 waves + resources for 4/EU).
// v8 = (2, 8): budget 128 (no spill), no runtime clamp. Steady state:
// LDS 75.8 KB -> 2 blocks/CU x 8 waves = 16 waves/CU = 4/EU.
// Grid (128 i-blocks, 4 b-quarters) x 512 threads (8 waves).
// Block = 16 b x 16 i. Wave w: bq = w&3 (owns b-quad by*16 + bq*4 + {0..3}),
// ih = w>>2 (owns i-half). Per round (4 rounds) stage 2 i from each half
// (4 i-slots); each wave consumes its half's 2 slots. Per-wave arithmetic
// (4-b amortization of W fragments, ds_read count, pair-softmax) identical
// to v1. End: cross-ih reduce through LDS; partial layout unchanged.
// Lane = (c = lane&31, dg = lane>>5).
// MODE 0: uniform coupling 1/32. MODE 1: logits = dot(u, veff),
// veff transposed [b][dg][c][8].
template <int MODE>
__global__
__attribute__((amdgpu_flat_work_group_size(512, 512), amdgpu_waves_per_eu(2, 8)))
void route_pass(
    const float* __restrict__ x, const float* __restrict__ W,
    const float* __restrict__ veff, float* __restrict__ partial)
{
    // W slots: float4 [slot 4 = ih*2+il][k10 16][kdg 2][c 32 + 1 pad]
    __shared__ float4 wbuf[4224];   // 67.6 KB
    __shared__ float4 xbuf[512];    // [brel 16][iloc 16][2] = 8 KB, staged once

    const int tid   = threadIdx.x;
    const int wave  = tid >> 6;
    const int lane  = tid & 63;
    const int c     = lane & 31;
    const int dg    = lane >> 5;
    const int bq    = wave & 3;
    const int ih    = wave >> 2;
    const int brel0 = bq * 4;
    const int b0    = blockIdx.y * 16 + brel0;    // wave's b-quad base
    const int i0    = blockIdx.x * 16;

    f8 s0 = {}, s1 = {}, s2 = {}, s3 = {};

    // veff fragments for the 4 b's (MODE 1), transposed [b][dg][c][8]
    f8 va = {}, vb = {}, vc = {}, vd = {};
    if (MODE == 1) {
        va = *reinterpret_cast<const f8*>(veff + (((size_t)(b0+0)*2 + dg)*32 + c)*8);
        vb = *reinterpret_cast<const f8*>(veff + (((size_t)(b0+1)*2 + dg)*32 + c)*8);
        vc = *reinterpret_cast<const f8*>(veff + (((size_t)(b0+2)*2 + dg)*32 + c)*8);
        vd = *reinterpret_cast<const f8*>(veff + (((size_t)(b0+3)*2 + dg)*32 + c)*8);
    }

    // ---- stage x once for all 16 i (coalesced 512 B per b-row)
    {
        const int brel = tid >> 5;
        const int q    = tid & 31;
        xbuf[tid] = reinterpret_cast<const float4*>(x)[
            ((size_t)(blockIdx.y * 16 + brel) * NI + i0) * 2 + q];
    }

    for (int rnd = 0; rnd < 4; ++rnd) {
        __syncthreads();               // previous round's readers done
        // ---- stage W: 4 i-rows (2 per half) x 32 c = 128 rows x 512 B
        {
            const int k    = tid & 31;        // float4 within a (c,i) row
            const int rowp = tid >> 5;        // 0..15
            const int k10 = k & 15, kdg = k >> 4;
#pragma unroll
            for (int r = 0; r < 8; ++r) {
                const int row = r * 16 + rowp;    // 0..127
                const int cc  = row >> 2;
                const int sub = row & 3;          // = slot = iih*2 + iil
                wbuf[((sub * 16 + k10) * 2 + kdg) * 33 + cc] =
                    reinterpret_cast<const float4*>(W)[
                        ((size_t)cc * NI + i0 + (sub >> 1) * 8 + rnd * 2
                         + (sub & 1)) * 32 + k];
            }
        }
        __syncthreads();

#pragma unroll
        for (int il = 0; il < 2; ++il) {
            const int slot = ih * 2 + il;
            const int iloc = ih * 8 + rnd * 2 + il;
            // x broadcast reads (wave-uniform LDS addresses)
            const float4 xa0 = xbuf[(brel0+0)*32 + iloc*2], xa1 = xbuf[(brel0+0)*32 + iloc*2+1];
            const float4 xb0 = xbuf[(brel0+1)*32 + iloc*2], xb1 = xbuf[(brel0+1)*32 + iloc*2+1];
            const float4 xc0 = xbuf[(brel0+2)*32 + iloc*2], xc1 = xbuf[(brel0+2)*32 + iloc*2+1];
            const float4 xd0 = xbuf[(brel0+3)*32 + iloc*2], xd1 = xbuf[(brel0+3)*32 + iloc*2+1];

            f8 u0 = {}, u1 = {}, u2 = {}, u3 = {};
#pragma unroll
            for (int dd = 0; dd < 8; ++dd) {
                const float4 wl = wbuf[((slot*16 + dd*2    )*2 + dg)*33 + c];
                const float4 wh = wbuf[((slot*16 + dd*2 + 1)*2 + dg)*33 + c];
                u0[dd] = wl.x*xa0.x + wl.y*xa0.y + wl.z*xa0.z + wl.w*xa0.w
                       + wh.x*xa1.x + wh.y*xa1.y + wh.z*xa1.z + wh.w*xa1.w;
                u1[dd] = wl.x*xb0.x + wl.y*xb0.y + wl.z*xb0.z + wl.w*xb0.w
                       + wh.x*xb1.x + wh.y*xb1.y + wh.z*xb1.z + wh.w*xb1.w;
                u2[dd] = wl.x*xc0.x + wl.y*xc0.y + wl.z*xc0.z + wl.w*xc0.w
                       + wh.x*xc1.x + wh.y*xc1.y + wh.z*xc1.z + wh.w*xc1.w;
                u3[dd] = wl.x*xd0.x + wl.y*xd0.y + wl.z*xd0.z + wl.w*xd0.w
                       + wh.x*xd1.x + wh.y*xd1.y + wh.z*xd1.z + wh.w*xd1.w;
            }

            if (MODE == 0) {
                const float cu = 1.0f / 32.0f;
                s0 += u0 * cu; s1 += u1 * cu; s2 += u2 * cu; s3 += u3 * cu;
            } else {
                // Pair-softmax: lower 32-half reduces the even b, upper the
                // odd b, concurrently; one xor-32 merge in, one xor-32
                // coef-swap out. 12 shuffles + 1 exp per pair.
#pragma unroll
                for (int pr = 0; pr < 2; ++pr) {
                    const f8& ue = pr ? u2 : u0;
                    const f8& uo = pr ? u3 : u1;
                    const f8& ve = pr ? vc : va;
                    const f8& vo = pr ? vd : vb;
                    float pe = 0.0f, po = 0.0f;
#pragma unroll
                    for (int k = 0; k < 8; ++k) {
                        pe += ue[k] * ve[k];
                        po += uo[k] * vo[k];
                    }
                    // route partial of the OTHER half's b across, keep mine
                    const float send = (dg == 0) ? po : pe;
                    const float recv = __shfl_xor(send, 32);
                    float a = ((dg == 0) ? pe : po) + recv;  // full logit
                    float m = a;
#pragma unroll
                    for (int off = 16; off >= 1; off >>= 1)
                        m = fmaxf(m, __shfl_xor(m, off));
                    const float e = __expf(a - m);
                    float t = e;
#pragma unroll
                    for (int off = 16; off >= 1; off >>= 1)
                        t += __shfl_xor(t, off);
                    const float mine  = e / t;
                    const float other = __shfl_xor(mine, 32);
                    const float ce = (dg == 0) ? mine : other;
                    const float co = (dg == 0) ? other : mine;
                    if (pr == 0) { s0 += u0 * ce; s1 += u1 * co; }
                    else         { s2 += u2 * ce; s3 += u3 * co; }
                }
            }
        }
    }

    // ---- cross-i-half merge: ih=1 waves dump s into (reused) wbuf,
    //      ih=0 waves add and store. Scratch: [brel 16][lane 64][2 f4] = 32 KB.
    __syncthreads();
    const int mbase = (brel0 * 64 + lane) * 2;
    if (ih == 1) {
        F8u t;
        t.v = s0; wbuf[mbase      ] = t.q[0]; wbuf[mbase +   1] = t.q[1];
        t.v = s1; wbuf[mbase + 128] = t.q[0]; wbuf[mbase + 129] = t.q[1];
        t.v = s2; wbuf[mbase + 256] = t.q[0]; wbuf[mbase + 257] = t.q[1];
        t.v = s3; wbuf[mbase + 384] = t.q[0]; wbuf[mbase + 385] = t.q[1];
    }
    __syncthreads();
    if (ih == 0) {
        F8u t;
        t.q[0] = wbuf[mbase      ]; t.q[1] = wbuf[mbase +   1]; s0 += t.v;
        t.q[0] = wbuf[mbase + 128]; t.q[1] = wbuf[mbase + 129]; s1 += t.v;
        t.q[0] = wbuf[mbase + 256]; t.q[1] = wbuf[mbase + 257]; s2 += t.v;
        t.q[0] = wbuf[mbase + 384]; t.q[1] = wbuf[mbase + 385]; s3 += t.v;

        // partial floats: [pblk 512][brel 16][dg 2][c 32][8]  (same as v1)
        const int pblk = blockIdx.y * gridDim.x + blockIdx.x;   // 0..511
        float* gp = partial +
            (((size_t)pblk * 16 + brel0) * 128 + dg * 64 + c * 2) * 4;
        *reinterpret_cast<f8*>(gp)        = s0;
        *reinterpret_cast<f8*>(gp +  512) = s1;
        *reinterpret_cast<f8*>(gp + 1024) = s2;
        *reinterpret_cast<f8*>(gp + 1536) = s3;
    }
}

// Fused 128-way partial reduction + squash, float4-vectorized.
// 64 blocks x 512 threads: tid -> (ibq = tid>>7 sums 32 of the 128 i-block
// slabs; sub = tid&127 -> (c = (sub>>2)&31, dq = sub&3)). 4-way LDS tree
// then squash on tid<128.
// phase 1: veff  = NI * squash(s)   (transposed layout [b][dg][c][8])
// phase 2: veff += NI * squash(s)
// phase 3: out   = squash(s)        (canonical [b][c][d])
__global__ __launch_bounds__(512) void reduce_squash(
    const float* __restrict__ partial, float* __restrict__ veff,
    float* __restrict__ out, int phase)
{
    __shared__ float4 red[512];
    const int b   = blockIdx.x;
    const int sub = threadIdx.x & 127;
    const int ibq = threadIdx.x >> 7;        // i-block quarter
    const int c   = (sub >> 2) & 31;
    const int dq  = sub & 3;                 // d-quad: d = dq*4 + j

    // slab layout: [by*128 + ib][brel 16][dg 2][c 32][8]
    const float* base = partial
        + ((size_t)(b >> 4) * 2048 + (b & 15)) * 512
        + (dq >> 1) * 256 + c * 8 + (dq & 1) * 4
        + (size_t)ibq * 32 * 8192;
    float4 acc = make_float4(0.f, 0.f, 0.f, 0.f);
#pragma unroll 8
    for (int ib = 0; ib < 32; ++ib) {
        const float4 p = *reinterpret_cast<const float4*>(base + (size_t)ib * 8192);
        acc.x += p.x; acc.y += p.y; acc.z += p.z; acc.w += p.w;
    }
    red[threadIdx.x] = acc;
    __syncthreads();
    if (threadIdx.x < 128) {
        const float4 a1 = red[sub + 128];
        const float4 a2 = red[sub + 256];
        const float4 a3 = red[sub + 384];
        acc.x += a1.x + a2.x + a3.x;
        acc.y += a1.y + a2.y + a3.y;
        acc.z += a1.z + a2.z + a3.z;
        acc.w += a1.w + a2.w + a3.w;

        // |s|^2 across the 4 d-quads (dq = low 2 bits of lane id)
        float sq = acc.x*acc.x + acc.y*acc.y + acc.z*acc.z + acc.w*acc.w;
        sq += __shfl_xor(sq, 1);
        sq += __shfl_xor(sq, 2);
        const float scale = sq / ((1.0f + sq) * sqrtf(sq + SQ_EPS));

        if (phase == 3) {
            float4* op = reinterpret_cast<float4*>(out + ((size_t)b * NC + c) * DC + dq * 4);
            *op = make_float4(scale*acc.x, scale*acc.y, scale*acc.z, scale*acc.w);
        } else {
            const float ns = scale * (float)NI;
            float4* vp = reinterpret_cast<float4*>(
                veff + (((size_t)b * 2 + (dq >> 1)) * 32 + c) * 8 + (dq & 1) * 4);
            if (phase == 1) {
                *vp = make_float4(ns*acc.x, ns*acc.y, ns*acc.z, ns*acc.w);
            } else {
                float4 old = *vp;
                *vp = make_float4(old.x + ns*acc.x, old.y + ns*acc.y,
                                  old.z + ns*acc.z, old.w + ns*acc.w);
            }
        }
    }
}

extern "C" void kernel_launch(void* const* d_in, const int* in_sizes, int n_in,
                              void* d_out, int out_size, void* d_ws, size_t ws_size,
                              hipStream_t stream) {
    (void)in_sizes; (void)n_in; (void)out_size; (void)ws_size;
    const float* x = (const float*)d_in[0];
    const float* W = (const float*)d_in[1];

    float* partial = (float*)d_ws;      // 512 slabs x 32 KB = 16 MiB
    float* veff    = (float*)d_out;     // scratch; phase-3 squash overwrites

    const dim3 grid(128, 4);

    // ---- iteration 1: uniform coupling
    route_pass<0><<<grid, 512, 0, stream>>>(x, W, nullptr, partial);
    reduce_squash<<<64, 512, 0, stream>>>(partial, veff, nullptr, 1);

    // ---- iteration 2: logits = NI * <u, v1>
    route_pass<1><<<grid, 512, 0, stream>>>(x, W, veff, partial);
    reduce_squash<<<64, 512, 0, stream>>>(partial, veff, nullptr, 2);

    // ---- iteration 3: logits = NI * (<u, v1> + <u, v2>)
    route_pass<1><<<grid, 512, 0, stream>>>(x, W, veff, partial);
    reduce_squash<<<64, 512, 0, stream>>>(partial, nullptr, (float*)d_out, 3);
}